// Round 10
// baseline (1725.632 us; speedup 1.0000x reference)
//
#include <hip/hip_runtime.h>
#include <stdint.h>

// ============================ problem constants ============================
constexpr int VOC  = 50257;
constexpr int VPAD = 50688;          // padded to multiple of 256 (8-phase tiles)
constexpr int DEMB = 768;
constexpr int NQ   = 4096;           // B*T
constexpr float EPS_HALF = 0.05f;    // EPSILON / 2
constexpr float LOG2E = 1.4426950408889634f;
constexpr float C16   = -23.083120654223414f;   // -16*log2(e); fixed softmax "max"
// logit = sim*0.05 + gumbel < 16 always; P = exp2(simraw*rk2 + C16) / (-ln u)

typedef __attribute__((ext_vector_type(4))) short    short4_t;
typedef __attribute__((ext_vector_type(8))) short    short8_t;
typedef __attribute__((ext_vector_type(4))) float    float4_t;
typedef __attribute__((ext_vector_type(4))) uint32_t uint4_t;

#define VMW(N) asm volatile("s_waitcnt vmcnt(" #N ")" ::: "memory")

// ============================ small helpers ================================
__device__ __forceinline__ short f2bf(float f) {   // RNE float->bf16
  uint32_t u = __float_as_uint(f);
  u += 0x7FFFu + ((u >> 16) & 1u);
  return (short)(u >> 16);
}

// ---- 8 independent threefry2x32 hashes, key (0,42), counters e0..e0+7 ----
__device__ __forceinline__ void tf8(uint32_t e0, uint32_t out[8]) {
  const uint32_t K0 = 0u, K1 = 42u, K2 = 0x1BD11BDAu ^ 42u;
  uint32_t x0[8], x1[8];
#pragma unroll
  for (int r = 0; r < 8; ++r) { x0[r] = K0; x1[r] = e0 + (uint32_t)r + K1; }
#define R8(a) _Pragma("unroll") \
  for (int r = 0; r < 8; ++r) { x0[r] += x1[r]; x1[r] = __builtin_rotateleft32(x1[r], a) ^ x0[r]; }
#define INJ8(a, b, i) _Pragma("unroll") \
  for (int r = 0; r < 8; ++r) { x0[r] += (a); x1[r] += (b) + (uint32_t)(i); }
  R8(13) R8(15) R8(26) R8(6)
  INJ8(K1, K2, 1)
  R8(17) R8(29) R8(16) R8(24)
  INJ8(K2, K0, 2)
  R8(13) R8(15) R8(26) R8(6)
  INJ8(K0, K1, 3)
  R8(17) R8(29) R8(16) R8(24)
  INJ8(K1, K2, 4)
  R8(13) R8(15) R8(26) R8(6)
#pragma unroll
  for (int r = 0; r < 8; ++r) { x0[r] += K2; x1[r] += K0 + 5u; out[r] = x0[r] ^ x1[r]; }
#undef R8
#undef INJ8
}

// t = -ln(u), u = n*2^-23. Branchless; series near u->1 avoids log cancellation.
__device__ __forceinline__ float neg_ln_u(uint32_t bits) {
  uint32_t n = bits >> 9;
  uint32_t m = 8388608u - n;
  float t_log = (23.0f - __builtin_amdgcn_logf((float)n)) * 0.69314718055994531f;
  float x = (float)m * 1.1920928955078125e-7f;
  float t_ser = x * fmaf(x, fmaf(x, fmaf(x, 0.25f, 0.3333333333f), 0.5f), 1.0f);
  return (m < 32768u) ? t_ser : t_log;
}

// ============================ prep kernels =================================
__global__ void k_prep_e(const float* __restrict__ E, short* __restrict__ Eb,
                         float* __restrict__ rk2) {
  int j = blockIdx.x;            // 0..VPAD-1
  int t = threadIdx.x;
  __shared__ float red[4];
  float ssq = 0.f;
  if (j < VOC) {
    if (t < 192) {
      float4_t v = *(const float4_t*)(E + (size_t)j * DEMB + t * 4);
      ssq = v[0]*v[0] + v[1]*v[1] + v[2]*v[2] + v[3]*v[3];
      short4_t b; b[0]=f2bf(v[0]); b[1]=f2bf(v[1]); b[2]=f2bf(v[2]); b[3]=f2bf(v[3]);
      *(short4_t*)(Eb + (size_t)j * DEMB + t * 4) = b;
    }
  } else if (t < 192) {
    short4_t z = {0,0,0,0};
    *(short4_t*)(Eb + (size_t)j * DEMB + t * 4) = z;
  }
  for (int off = 32; off; off >>= 1) ssq += __shfl_xor(ssq, off);
  if ((t & 63) == 0) red[t >> 6] = ssq;
  __syncthreads();
  if (t == 0) {
    float s = red[0] + red[1] + red[2] + red[3];
    rk2[j] = (j < VOC) ? (EPS_HALF * LOG2E / fmaxf(sqrtf(s), 1e-12f)) : 0.f;
  }
}

__global__ void k_prep_q(const int* __restrict__ ids, const float* __restrict__ E,
                         short* __restrict__ qn) {
  int p = blockIdx.x;
  int t = threadIdx.x;
  int id = ids[p];
  __shared__ float red[4];
  __shared__ float scale_s;
  float4_t v = {0.f, 0.f, 0.f, 0.f};
  float ssq = 0.f;
  if (t < 192) {
    v = *(const float4_t*)(E + (size_t)id * DEMB + t * 4);
    ssq = v[0]*v[0] + v[1]*v[1] + v[2]*v[2] + v[3]*v[3];
  }
  for (int off = 32; off; off >>= 1) ssq += __shfl_xor(ssq, off);
  if ((t & 63) == 0) red[t >> 6] = ssq;
  __syncthreads();
  if (t == 0) scale_s = 1.0f / fmaxf(sqrtf(red[0]+red[1]+red[2]+red[3]), 1e-12f);
  __syncthreads();
  float sc = scale_s;
  if (t < 192) {
    short4_t b; b[0]=f2bf(v[0]*sc); b[1]=f2bf(v[1]*sc); b[2]=f2bf(v[2]*sc); b[3]=f2bf(v[3]*sc);
    *(short4_t*)(qn + (size_t)p * DEMB + t * 4) = b;
  }
}

// Et[d][key] = Eb[key][d]   (row-major, stride VPAD)
__global__ void k_transpose(const short* __restrict__ Eb, short* __restrict__ Et) {
  int lane = threadIdx.x & 63;
  int dg   = threadIdx.x >> 6;
  int key  = blockIdx.x * 64 + lane;
  int d0   = blockIdx.y * 32 + dg * 8;
  short8_t v = *(const short8_t*)(Eb + (size_t)key * DEMB + d0);
#pragma unroll
  for (int q = 0; q < 8; ++q)
    Et[(size_t)(d0 + q) * VPAD + key] = v[q];
}

__global__ void k_zero(float* __restrict__ O, float* __restrict__ lsum) {
  int idx = blockIdx.x * 256 + threadIdx.x;      // float4 index over O
  if (idx < NQ) lsum[idx] = 0.f;
  float4_t z = {0.f, 0.f, 0.f, 0.f};
  ((float4_t*)O)[idx] = z;
}

// ===================== 8-phase 256-tile GEMM plumbing ======================
// LDS image per 64-col tile: LDS[row][s] = g[row][s ^ ((row&7)<<3)]  (shorts)
// -> fragment column reads are 2-way bank aliased (free).  Staged with
// global_load_lds: linear LDS dest, pre-swizzled SOURCE column.
__device__ __forceinline__ int swz(int row, int byte) {
  return (row << 7) + (byte ^ ((row & 7) << 4));
}

template<int PASSES>   // PASSES = rows/64 with 512 threads
__device__ __forceinline__ void stage512(short* L, const short* __restrict__ g,
                                         long grow0, long stride, long col0, int tid) {
  int c8 = (tid & 7) << 3;
  int r0 = tid >> 3;
#pragma unroll
  for (int i = 0; i < PASSES; ++i) {
    int  row = r0 + i * 64;
    long cs  = (long)(c8 ^ ((row & 7) << 3));
    const short* src = g + (grow0 + row) * stride + col0 + cs;
    short* dst = L + row * 64 + c8;
    __builtin_amdgcn_global_load_lds(
        (const __attribute__((address_space(1))) void*)src,
        (__attribute__((address_space(3))) void*)dst, 16, 0, 0);
  }
}

__device__ __forceinline__ short8_t ldfrag(const short* L, int row, int kbyte) {
  return *(const short8_t*)(L + (swz(row, kbyte) >> 1));
}

__device__ __forceinline__ float4_t mfma16(short8_t a, short8_t b, float4_t c) {
  return __builtin_amdgcn_mfma_f32_16x16x32_bf16(a, b, c, 0, 0, 0);
}

// ---- GEMM1: S[p][jc] = qn_p . Eb_j  (raw sim, f16). 256x256 tile, 8 waves,
// BK=64, dbuf LDS 128KB, counted vmcnt(8), 4 phases/K-tile, setprio on MFMA.
__global__ __launch_bounds__(512) void k_gemm1(
    const short* __restrict__ qn, const short* __restrict__ Eb,
    _Float16* __restrict__ S, int c0, int KC) {
  extern __shared__ short lds[];
  short* A0 = lds;                          // [2][256*64]
  short* B0 = lds + 2 * 256 * 64;           // [2][256*64]
  int tid = threadIdx.x, lane = tid & 63;
  int wid = tid >> 6, wm = wid >> 2, wn = wid & 3;   // 2 x 4 wave grid
  int rowbase = blockIdx.x * 256;
  long colg   = (long)c0 + blockIdx.y * 256;         // global col of tile
  float4_t acc[8][4];
  float4_t zero = {0.f, 0.f, 0.f, 0.f};
#pragma unroll
  for (int mt = 0; mt < 8; ++mt)
#pragma unroll
    for (int nt = 0; nt < 4; ++nt) acc[mt][nt] = zero;

  const int n = DEMB / 64;                  // 12 K-tiles
  stage512<4>(A0, qn, rowbase, DEMB, 0, tid);
  stage512<4>(B0, Eb, colg,    DEMB, 0, tid);
  for (int kt = 0; kt < n; ++kt) {
    int cur = kt & 1;
    if (kt + 1 < n) {
      stage512<4>(A0 + (cur ^ 1) * (256 * 64), qn, rowbase, DEMB, (kt + 1) * 64, tid);
      stage512<4>(B0 + (cur ^ 1) * (256 * 64), Eb, colg,    DEMB, (kt + 1) * 64, tid);
      VMW(8);                               // tile kt landed; kt+1's 8 stay in flight
    } else {
      VMW(0);
    }
    __builtin_amdgcn_s_barrier();
    const short* Al = A0 + cur * (256 * 64);
    const short* Bl = B0 + cur * (256 * 64);
#pragma unroll
    for (int ks = 0; ks < 2; ++ks) {
      int kb = ks * 64 + (lane >> 4) * 16;
      short8_t b4[4];
#pragma unroll
      for (int nt = 0; nt < 4; ++nt) b4[nt] = ldfrag(Bl, wn * 64 + nt * 16 + (lane & 15), kb);
#pragma unroll
      for (int mh = 0; mh < 2; ++mh) {      // phase = (ks, mh)
        short8_t a4[4];
#pragma unroll
        for (int j = 0; j < 4; ++j)
          a4[j] = ldfrag(Al, wm * 128 + mh * 64 + j * 16 + (lane & 15), kb);
        __builtin_amdgcn_s_setprio(1);
#pragma unroll
        for (int j = 0; j < 4; ++j)
#pragma unroll
          for (int nt = 0; nt < 4; ++nt)
            acc[mh * 4 + j][nt] = mfma16(a4[j], b4[nt], acc[mh * 4 + j][nt]);
        __builtin_amdgcn_s_setprio(0);
        __builtin_amdgcn_s_barrier();
      }
    }
  }
  // epilogue: raw sims -> f16 (C/D: col = lane&15, row = (lane>>4)*4 + reg)
#pragma unroll
  for (int mt = 0; mt < 8; ++mt) {
    int prow = rowbase + wm * 128 + mt * 16 + ((lane >> 4) << 2);
    int jc0  = blockIdx.y * 256 + wn * 64 + (lane & 15);
#pragma unroll
    for (int r = 0; r < 4; ++r) {
      _Float16* dst = S + (size_t)(prow + r) * KC + jc0;
#pragma unroll
      for (int nt = 0; nt < 4; ++nt) dst[nt * 16] = (_Float16)acc[mt][nt][r];
    }
  }
}

// ---- gumbel/softmax pass: in-place f16 sim -> bf16 P, + row-sum atomics ----
__global__ __launch_bounds__(256) void k_gumbel(
    uint32_t* __restrict__ SP, const float* __restrict__ rk2,
    float* __restrict__ lsum, int c0, int KCeff, int KC) {
  int p    = blockIdx.x;
  int colq = blockIdx.y * 2048 + threadIdx.x * 8;
  float partial = 0.f;
  if (colq < KCeff) {
    uint32_t* base = SP + ((size_t)p * KC + colq) / 2;     // 2B elems -> u32 pairs
    uint4_t sv = *(const uint4_t*)base;                    // 8 f16 sims
    int j0 = c0 + colq;                                    // global vocab col
    float4_t rk_lo = *(const float4_t*)(rk2 + j0);
    float4_t rk_hi = *(const float4_t*)(rk2 + j0 + 4);
    uint32_t bits[8];
    tf8((uint32_t)p * (uint32_t)VOC + (uint32_t)j0, bits);
    float pe[8];
#pragma unroll
    for (int i = 0; i < 8; ++i) {
      uint32_t h = (sv[i >> 1] >> ((i & 1) * 16)) & 0xFFFFu;
      _Float16 hf = *(_Float16*)&h;
      float simf = (float)hf;
      float rkj = (i < 4) ? rk_lo[i] : rk_hi[i - 4];
      float t = neg_ln_u(bits[i]);
      float v = __builtin_amdgcn_exp2f(fmaf(simf, rkj, C16)) * __builtin_amdgcn_rcpf(t);
      bool ok = (j0 + i) < VOC;
      pe[i] = ok ? v : 0.f;
      partial += pe[i];
    }
    uint4_t pkv;
#pragma unroll
    for (int i = 0; i < 4; ++i) {
      uint32_t r;
      asm("v_cvt_pk_bf16_f32 %0, %1, %2" : "=v"(r) : "v"(pe[2 * i]), "v"(pe[2 * i + 1]));
      pkv[i] = r;
    }
    *(uint4_t*)base = pkv;
  }
  for (int off = 32; off; off >>= 1) partial += __shfl_xor(partial, off);
  if ((threadIdx.x & 63) == 0 && partial != 0.f) unsafeAtomicAdd(&lsum[p], partial);
}

// ---- GEMM2: O[p][d] += sum_k P[p][k] * Et[d][k].  256x128 tile, 8 waves,
// BK=64, dbuf LDS 96KB, counted vmcnt(6), split-K=8 atomics.
__global__ __launch_bounds__(512) void k_gemm2(
    const short* __restrict__ P, const short* __restrict__ Et,
    float* __restrict__ O, int c0, int KC, int kseg) {
  extern __shared__ short lds[];
  short* A0 = lds;                          // [2][256*64]
  short* B0 = lds + 2 * 256 * 64;           // [2][128*64]
  int tid = threadIdx.x, lane = tid & 63;
  int wid = tid >> 6, wm = wid >> 2, wn = wid & 3;
  int rowbase = blockIdx.x * 256;           // q
  int colbase = blockIdx.y * 128;           // d
  long kbase  = (long)blockIdx.z * kseg;    // within chunk
  float4_t acc[8][2];
  float4_t zero = {0.f, 0.f, 0.f, 0.f};
#pragma unroll
  for (int mt = 0; mt < 8; ++mt)
#pragma unroll
    for (int nt = 0; nt < 2; ++nt) acc[mt][nt] = zero;

  const int n = kseg / 64;
  stage512<4>(A0, P,  rowbase, KC,   kbase, tid);
  stage512<2>(B0, Et, colbase, VPAD, (long)c0 + kbase, tid);
  for (int kt = 0; kt < n; ++kt) {
    int cur = kt & 1;
    if (kt + 1 < n) {
      stage512<4>(A0 + (cur ^ 1) * (256 * 64), P,  rowbase, KC,   kbase + (kt + 1) * 64, tid);
      stage512<2>(B0 + (cur ^ 1) * (128 * 64), Et, colbase, VPAD, (long)c0 + kbase + (kt + 1) * 64, tid);
      VMW(6);
    } else {
      VMW(0);
    }
    __builtin_amdgcn_s_barrier();
    const short* Al = A0 + cur * (256 * 64);
    const short* Bl = B0 + cur * (128 * 64);
#pragma unroll
    for (int ks = 0; ks < 2; ++ks) {
      int kb = ks * 64 + (lane >> 4) * 16;
      short8_t b2[2];
#pragma unroll
      for (int nt = 0; nt < 2; ++nt) b2[nt] = ldfrag(Bl, wn * 32 + nt * 16 + (lane & 15), kb);
#pragma unroll
      for (int mh = 0; mh < 2; ++mh) {
        short8_t a4[4];
#pragma unroll
        for (int j = 0; j < 4; ++j)
          a4[j] = ldfrag(Al, wm * 128 + mh * 64 + j * 16 + (lane & 15), kb);
        __builtin_amdgcn_s_setprio(1);
#pragma unroll
        for (int j = 0; j < 4; ++j)
#pragma unroll
          for (int nt = 0; nt < 2; ++nt)
            acc[mh * 4 + j][nt] = mfma16(a4[j], b2[nt], acc[mh * 4 + j][nt]);
        __builtin_amdgcn_s_setprio(0);
        __builtin_amdgcn_s_barrier();
      }
    }
  }
#pragma unroll
  for (int mt = 0; mt < 8; ++mt)
#pragma unroll
    for (int nt = 0; nt < 2; ++nt) {
      int d = colbase + wn * 32 + nt * 16 + (lane & 15);
#pragma unroll
      for (int r = 0; r < 4; ++r) {
        int p = rowbase + wm * 128 + mt * 16 + ((lane >> 4) << 2) + r;
        unsafeAtomicAdd(&O[(size_t)p * DEMB + d], acc[mt][nt][r]);
      }
    }
}

__global__ void k_finalize(const float* __restrict__ O, const float* __restrict__ lsum,
                           float* __restrict__ out) {
  int idx = blockIdx.x * 256 + threadIdx.x;      // float4 index
  float inv = 1.0f / lsum[idx / 192];            // 192 float4 per row
  float4_t v = ((const float4_t*)O)[idx];
  v[0]*=inv; v[1]*=inv; v[2]*=inv; v[3]*=inv;
  ((float4_t*)out)[idx] = v;
}

// ============================ host launcher ================================
extern "C" void kernel_launch(void* const* d_in, const int* in_sizes, int n_in,
                              void* d_out, int out_size, void* d_ws, size_t ws_size,
                              hipStream_t stream) {
  (void)in_sizes; (void)n_in; (void)out_size;
  const int*   ids = (const int*)d_in[0];
  const float* E   = (const float*)d_in[1];
  float*       out = (float*)d_out;

  // allow >64KB dynamic LDS (idempotent; not a graph-capture hazard)
  hipFuncSetAttribute((const void*)k_gemm1, hipFuncAttributeMaxDynamicSharedMemorySize, 128 * 1024);
  hipFuncSetAttribute((const void*)k_gemm2, hipFuncAttributeMaxDynamicSharedMemorySize, 96 * 1024);

  char* w = (char*)d_ws;
  short* Eb = (short*)w;      w += (size_t)VPAD * DEMB * 2;   // 77.9 MB
  short* Et = (short*)w;      w += (size_t)DEMB * VPAD * 2;   // 77.9 MB
  short* qn = (short*)w;      w += (size_t)NQ * DEMB * 2;     // 6.3 MB
  float* O  = (float*)w;      w += (size_t)NQ * DEMB * 4;     // 12.6 MB
  float* rk2 = (float*)w;     w += (size_t)VPAD * 4;
  float* lsum = (float*)w;    w += NQ * 4;
  void*  SP = (void*)w;       // f16 sim chunk, overwritten in-place with bf16 P
  size_t fixed = (size_t)(w - (char*)d_ws);

  int KC = 2048;
  if      (fixed + (size_t)NQ * 8192 * 2 <= ws_size) KC = 8192;
  else if (fixed + (size_t)NQ * 4096 * 2 <= ws_size) KC = 4096;
  int chunks = (VPAD + KC - 1) / KC;

  k_zero<<<(NQ * DEMB / 4) / 256, 256, 0, stream>>>(O, lsum);
  k_prep_e<<<VPAD, 256, 0, stream>>>(E, Eb, rk2);
  k_prep_q<<<NQ, 256, 0, stream>>>(ids, E, qn);
  k_transpose<<<dim3(VPAD / 64, DEMB / 32), 256, 0, stream>>>(Eb, Et);

  for (int c = 0; c < chunks; ++c) {
    int c0 = c * KC;
    int KCeff = VPAD - c0; if (KCeff > KC) KCeff = KC;        // multiple of 256
    k_gemm1<<<dim3(NQ / 256, KCeff / 256), 512, 128 * 1024, stream>>>(
        qn, Eb, (_Float16*)SP, c0, KC);
    k_gumbel<<<dim3(NQ, (KCeff + 2047) / 2048), 256, 0, stream>>>(
        (uint32_t*)SP, rk2, lsum, c0, KCeff, KC);
    int kseg = KCeff / 8;                                     // always multiple of 64
    k_gemm2<<<dim3(NQ / 256, DEMB / 128, 8), 512, 96 * 1024, stream>>>(
        (const short*)SP, Et, O, c0, KC, kseg);
  }
  k_finalize<<<(NQ * DEMB / 4) / 256, 256, 0, stream>>>(O, lsum, out);
}